// Round 9
// baseline (1133.348 us; speedup 1.0000x reference)
//
#include <hip/hip_runtime.h>
#include <cstddef>

// ---------------- problem constants ----------------
#define Bq    4
#define Hh    12
#define Dd    64
#define NNtok 1280
#define DIMc  768
#define KAUG  800      // 768 + 32 augmented-K for fused LoRA
#define NBH   48       // Bq*Hh

typedef __attribute__((ext_vector_type(8))) short bf16x8;
typedef __attribute__((ext_vector_type(4))) float f32x4;

// workspace offsets (floats)
static const size_t OVb   = 0;                   // vb fp32 (B,H,1280,64); rows 0-255 -> v_add_id
static const size_t OXO   = 3932160;             // xo fp32 (B,1280,768)
static const size_t OQL   = 7864320;             // qkv low (5120,24)
static const size_t OIDK  = 7987200;             // 1+tanh(ID_K) (1024,12)
static const size_t OIDV  = 7999488;             // ID_V (1024,768)
static const size_t OLK   = 8785920;             // id_lowk (1024,8)
static const size_t OLV   = 8794112;             // id_lowv (1024,8)
static const size_t ORD   = 8802304;             // route dots (5120,4)
static const size_t OPL   = 8822784;             // proj low (5120,32)
static const size_t OQH   = 8986624;             // qh bf16 (B,H,1280,64)
static const size_t OKFH  = 10952704;            // kfh bf16 (B,H,2560,64) [mem_k|k]
static const size_t OVTH  = 14884864;            // vth bf16 (B,H,64,2560)
static const size_t OKMH  = 18817024;            // kmh bf16 (B,H,256,64)
static const size_t OVMTH = 19210240;            // vmth bf16 (B,H,64,256)
static const size_t OAa   = 19603456;            // A_aug bf16 (5120,800)
static const size_t OWa   = 21651456;            // W_aug qkv bf16 (2304,800)
static const size_t OWa2  = 22573056;            // W_aug proj bf16 (768,800)

// d_out offsets (floats)
static const size_t KMID_OFF = 3932160;
static const size_t VMID_OFF = 4718592;

__device__ __forceinline__ unsigned int pk_bf16(float a, float b) {  // RNE pack
  unsigned int ua = __float_as_uint(a), ub = __float_as_uint(b);
  ua += 0x7fffu + ((ua >> 16) & 1u);
  ub += 0x7fffu + ((ub >> 16) & 1u);
  return (ua >> 16) | (ub & 0xffff0000u);
}
__device__ __forceinline__ unsigned short bf16_1(float a) {
  unsigned int ua = __float_as_uint(a);
  ua += 0x7fffu + ((ua >> 16) & 1u);
  return (unsigned short)(ua >> 16);
}
__device__ __forceinline__ float bf2f(unsigned int h) {
  return __uint_as_float(h << 16);
}

// ---------------- prep: cast_k | transpose(mem_v) | cast_w_qkv | cast_w_proj ----------------
__global__ __launch_bounds__(256) void prep(
    const float* __restrict__ mem_k, const float* __restrict__ mem_v,
    const float* __restrict__ W_qkv, const float* __restrict__ qkvB,
    const float* __restrict__ W_proj, const float* __restrict__ projB,
    unsigned short* __restrict__ kfh, unsigned short* __restrict__ vth,
    unsigned short* __restrict__ Wa, unsigned short* __restrict__ Wa2)
{
  __shared__ float tl[64][65];
  const int blk = blockIdx.x, t = threadIdx.x;
  if (blk < 1920) {                       // cast mem_k -> kfh rows 0..1279
    size_t idx = ((size_t)blk * 256 + t) * 8;
    int bh = (int)(idx / 81920);
    int r  = (int)(idx % 81920);
    const float* s = mem_k + (size_t)bh * 81920 + r;
    float4 a = *(const float4*)s;
    float4 b = *(const float4*)(s + 4);
    unsigned int* dp = (unsigned int*)(kfh + (size_t)bh * 163840 + r);
    dp[0] = pk_bf16(a.x, a.y); dp[1] = pk_bf16(a.z, a.w);
    dp[2] = pk_bf16(b.x, b.y); dp[3] = pk_bf16(b.z, b.w);
  } else if (blk < 2880) {                // transpose mem_v -> vth cols 0..1279
    int b2 = blk - 1920;
    int bh = b2 / 20, t0 = (b2 % 20) * 64;
    const float* sb = mem_v + (size_t)bh * 81920 + (size_t)t0 * 64;
#pragma unroll
    for (int p = 0; p < 4; ++p) {
      int flat = p * 256 + t;
      int r = flat >> 4, c4 = (flat & 15) << 2;
      float4 v = *(const float4*)(sb + r * 64 + c4);
      tl[r][c4 + 0] = v.x; tl[r][c4 + 1] = v.y;
      tl[r][c4 + 2] = v.z; tl[r][c4 + 3] = v.w;
    }
    __syncthreads();
    unsigned short* db = vth + (size_t)bh * 163840 + t0;
#pragma unroll
    for (int p = 0; p < 8; ++p) {
      int flat = p * 256 + t;
      int d = flat >> 5, u = flat & 31;
      *(unsigned int*)(db + (size_t)d * 2560 + 2 * u) = pk_bf16(tl[2 * u][d], tl[2 * u + 1][d]);
    }
  } else if (blk < 6480) {                // W_aug qkv
    int idx = (blk - 2880) * 256 + t;     // 2304*400 uint pairs
    int row = idx / 400, c = (idx % 400) * 2;
    float a, b;
    if (c < 768) {
      a = W_qkv[(size_t)row * 768 + c]; b = W_qkv[(size_t)row * 768 + c + 1];
    } else {
      int g = row / 768, jj = row % 768;
      int e0 = c - 768, e1 = e0 + 1;
      a = (e0 < 24 && (e0 >> 3) == g) ? qkvB[(size_t)g * 6144 + jj * 8 + (e0 & 7)] * 0.125f : 0.f;
      b = (e1 < 24 && (e1 >> 3) == g) ? qkvB[(size_t)g * 6144 + jj * 8 + (e1 & 7)] * 0.125f : 0.f;
    }
    *(unsigned int*)(Wa + (size_t)row * KAUG + c) = pk_bf16(a, b);
  } else {                                // W_aug proj
    int idx = (blk - 6480) * 256 + t;     // 768*400
    int row = idx / 400, c = (idx % 400) * 2;
    float a, b;
    if (c < 768) {
      a = W_proj[(size_t)row * 768 + c]; b = W_proj[(size_t)row * 768 + c + 1];
    } else {
      int e0 = c - 768, e1 = e0 + 1;
      a = projB[(size_t)(e0 >> 3) * 6144 + row * 8 + (e0 & 7)];
      b = projB[(size_t)(e1 >> 3) * 6144 + row * 8 + (e1 & 7)];
    }
    *(unsigned int*)(Wa2 + (size_t)row * KAUG + c) = pk_bf16(a, b);
  }
}

// ---------------- small row-dot kernel ----------------
__global__ __launch_bounds__(256) void dot_small(
    const float* __restrict__ src, const float* __restrict__ mat,
    float* __restrict__ dst, int nout)
{
  int wv = threadIdx.x >> 6, ln = threadIdx.x & 63;
  size_t row = (size_t)blockIdx.x * 4 + wv;
  const float* s = src + row * DIMc;
  for (int o = 0; o < nout; ++o) {
    float p = 0.f;
    const float* m = mat + (size_t)o * DIMc;
    for (int c = ln; c < DIMc; c += 64) p += s[c] * m[c];
    for (int off = 32; off; off >>= 1) p += __shfl_xor(p, off, 64);
    if (ln == 0) dst[row * nout + o] = p;
  }
}

// ---------------- fused id lora downs: lowk(8) + lowv(8) ----------------
__global__ __launch_bounds__(256) void dot_id(
    const float* __restrict__ id_tot, const float* __restrict__ idkA,
    const float* __restrict__ idvA, float* __restrict__ lowk,
    float* __restrict__ lowv)
{
  int wv = threadIdx.x >> 6, ln = threadIdx.x & 63;
  size_t row = (size_t)blockIdx.x * 4 + wv;
  const float* s = id_tot + row * DIMc;
  for (int o = 0; o < 8; ++o) {
    float p = 0.f, q = 0.f;
    const float* m1 = idkA + (size_t)o * DIMc;
    const float* m2 = idvA + (size_t)o * DIMc;
    for (int c = ln; c < DIMc; c += 64) { p += s[c] * m1[c]; q += s[c] * m2[c]; }
    for (int off = 32; off; off >>= 1) { p += __shfl_xor(p, off, 64); q += __shfl_xor(q, off, 64); }
    if (ln == 0) { lowk[row * 8 + o] = p; lowv[row * 8 + o] = q; }
  }
}

// ---------------- fused route+plow dots ----------------
__global__ __launch_bounds__(256) void dot_rp(
    const float* __restrict__ xo, const float* __restrict__ routeW,
    const float* __restrict__ projA, float* __restrict__ rd,
    float* __restrict__ plow)
{
  int wv = threadIdx.x >> 6, ln = threadIdx.x & 63;
  size_t row = (size_t)blockIdx.x * 4 + wv;
  const float* s = xo + row * DIMc;
  float xr[12];
#pragma unroll
  for (int i = 0; i < 12; ++i) xr[i] = s[ln + i * 64];
  for (int o = 0; o < 4; ++o) {
    float p = 0.f;
    const float* m = routeW + (size_t)o * DIMc;
#pragma unroll
    for (int i = 0; i < 12; ++i) p += xr[i] * m[ln + i * 64];
    for (int off = 32; off; off >>= 1) p += __shfl_xor(p, off, 64);
    if (ln == 0) rd[row * 4 + o] = p;
  }
  for (int o = 0; o < 32; ++o) {
    float p = 0.f;
    const float* m = projA + (size_t)o * DIMc;
#pragma unroll
    for (int i = 0; i < 12; ++i) p += xr[i] * m[ln + i * 64];
    for (int off = 32; off; off >>= 1) p += __shfl_xor(p, off, 64);
    if (ln == 0) plow[row * 32 + o] = p;
  }
}

// ---------------- ID_K: 1+tanh(lora1(...)) ----------------
__global__ __launch_bounds__(256) void idk_kernel(
    const float* __restrict__ id_tot, const float* __restrict__ W_idk,
    const float* __restrict__ b_idk, const float* __restrict__ lowk,
    const float* __restrict__ idk_B, float* __restrict__ IDK)
{
  int wv = threadIdx.x >> 6, ln = threadIdx.x & 63;
  size_t row = (size_t)blockIdx.x * 4 + wv;
  const float* s = id_tot + row * DIMc;
  for (int h = 0; h < Hh; ++h) {
    float p = 0.f;
    const float* m = W_idk + (size_t)h * DIMc;
    for (int c = ln; c < DIMc; c += 64) p += s[c] * m[c];
    for (int off = 32; off; off >>= 1) p += __shfl_xor(p, off, 64);
    if (ln == 0) {
      float lo = 0.f;
      for (int r = 0; r < 8; ++r) lo += lowk[row * 8 + r] * idk_B[h * 8 + r];
      IDK[row * Hh + h] = 1.f + tanhf(p + b_idk[h] + lo * 0.125f);
    }
  }
}

// ---------------- fixup: kmid holds raw k; multiply by IDK in place; v add IDV ----------------
__global__ __launch_bounds__(256) void fixup_kernel(
    float* __restrict__ vb, const float* __restrict__ IDK,
    const float* __restrict__ IDV, float* __restrict__ kmid,
    float* __restrict__ vmid, unsigned short* __restrict__ kmh)
{
  int e = blockIdx.x * 256 + threadIdx.x;   // flat (b,h,tt,d), tt<256
  int d  = e & 63;
  int r1 = e >> 6;
  int tt = r1 & 255;
  int r2 = r1 >> 8;
  int h  = r2 % Hh;
  int b  = r2 / Hh;
  float km = kmid[e] * IDK[(size_t)(b * 256 + tt) * Hh + h];
  kmid[e] = km;
  kmh[e] = bf16_1(km);
  size_t src = ((size_t)(b * Hh + h) * NNtok + tt) * Dd + d;
  float vv = vb[src] + IDV[(size_t)(b * 256 + tt) * DIMc + h * 64 + d];
  vb[src] = vv;
  vmid[e] = vv;
}

// ---------------- post-fixup transposes ----------------
__global__ __launch_bounds__(256) void transpose_post(
    const float* __restrict__ vb, unsigned short* __restrict__ vth,
    unsigned short* __restrict__ vmth)
{
  __shared__ float tl[64][65];
  const int blk = blockIdx.x, t = threadIdx.x;
  int bh, t0, dstCols, colOfs;
  unsigned short* dstp;
  size_t dstBh;
  if (blk < 960) { bh = blk / 20; t0 = (blk % 20) * 64; dstp = vth; dstBh = 163840; dstCols = 2560; colOfs = 1280; }
  else { int b2 = blk - 960; bh = b2 / 4; t0 = (b2 % 4) * 64; dstp = vmth; dstBh = 16384; dstCols = 256; colOfs = 0; }
  const float* sb = vb + (size_t)bh * 81920 + (size_t)t0 * 64;
#pragma unroll
  for (int p = 0; p < 4; ++p) {
    int flat = p * 256 + t;
    int r = flat >> 4, c4 = (flat & 15) << 2;
    float4 v = *(const float4*)(sb + r * 64 + c4);
    tl[r][c4 + 0] = v.x; tl[r][c4 + 1] = v.y;
    tl[r][c4 + 2] = v.z; tl[r][c4 + 3] = v.w;
  }
  __syncthreads();
  unsigned short* db = dstp + (size_t)bh * dstBh + colOfs + t0;
#pragma unroll
  for (int p = 0; p < 8; ++p) {
    int flat = p * 256 + t;
    int d = flat >> 5, u = flat & 31;
    *(unsigned int*)(db + (size_t)d * dstCols + 2 * u) = pk_bf16(tl[2 * u][d], tl[2 * u + 1][d]);
  }
}

// ---------------- pack A_aug for qkv ----------------
__global__ __launch_bounds__(256) void cast_pack(
    const float* __restrict__ mainp, const float* __restrict__ extra,
    unsigned short* __restrict__ dst, int extraN)
{
  int idx = blockIdx.x * 256 + threadIdx.x;    // 5120*100 groups of 8
  int row = idx / 100, c8 = (idx % 100) * 8;
  unsigned int w[4];
  if (c8 < 768) {
    const float* s = mainp + (size_t)row * 768 + c8;
    float4 a = *(const float4*)s;
    float4 b = *(const float4*)(s + 4);
    w[0] = pk_bf16(a.x, a.y); w[1] = pk_bf16(a.z, a.w);
    w[2] = pk_bf16(b.x, b.y); w[3] = pk_bf16(b.z, b.w);
  } else {
    float v[8];
#pragma unroll
    for (int j = 0; j < 8; ++j) {
      int e = c8 - 768 + j;
      v[j] = (e < extraN) ? extra[(size_t)row * extraN + e] : 0.f;
    }
    w[0] = pk_bf16(v[0], v[1]); w[1] = pk_bf16(v[2], v[3]);
    w[2] = pk_bf16(v[4], v[5]); w[3] = pk_bf16(v[6], v[7]);
  }
  *(uint4*)(dst + (size_t)row * KAUG + c8) = make_uint4(w[0], w[1], w[2], w[3]);
}

// ---------------- pack A_aug for proj (inline softmax(rd)*plow/8) ----------------
__global__ __launch_bounds__(256) void cast_pack_proj(
    const float* __restrict__ xo, const float* __restrict__ rd,
    const float* __restrict__ plow, unsigned short* __restrict__ dst)
{
  int idx = blockIdx.x * 256 + threadIdx.x;
  int row = idx / 100, c8 = (idx % 100) * 8;
  unsigned int w[4];
  if (c8 < 768) {
    const float* s = xo + (size_t)row * 768 + c8;
    float4 a = *(const float4*)s;
    float4 b = *(const float4*)(s + 4);
    w[0] = pk_bf16(a.x, a.y); w[1] = pk_bf16(a.z, a.w);
    w[2] = pk_bf16(b.x, b.y); w[3] = pk_bf16(b.z, b.w);
  } else {
    float l0 = rd[row * 4 + 0], l1 = rd[row * 4 + 1], l2 = rd[row * 4 + 2], l3 = rd[row * 4 + 3];
    float m = fmaxf(fmaxf(l0, l1), fmaxf(l2, l3));
    float e0 = __expf(l0 - m), e1 = __expf(l1 - m), e2 = __expf(l2 - m), e3 = __expf(l3 - m);
    float inv = 0.125f / (e0 + e1 + e2 + e3);
    float rt[4] = { e0 * inv, e1 * inv, e2 * inv, e3 * inv };
    float v[8];
#pragma unroll
    for (int j = 0; j < 8; ++j) {
      int e = c8 - 768 + j;
      v[j] = (e < 32) ? rt[e >> 3] * plow[(size_t)row * 32 + e] : 0.f;
    }
    w[0] = pk_bf16(v[0], v[1]); w[1] = pk_bf16(v[2], v[3]);
    w[2] = pk_bf16(v[4], v[5]); w[3] = pk_bf16(v[6], v[7]);
  }
  *(uint4*)(dst + (size_t)row * KAUG + c8) = make_uint4(w[0], w[1], w[2], w[3]);
}

// ---------------- MFMA GEMM: C = A_aug @ W_aug^T + bias, K=800 ----------------
__global__ __launch_bounds__(256) void gemm_mfma(
    const unsigned short* __restrict__ A, const unsigned short* __restrict__ W,
    const float* __restrict__ bias, int mode, float* __restrict__ dst,
    unsigned short* __restrict__ qh, float* __restrict__ kmid,
    float* __restrict__ vb, unsigned short* __restrict__ kfh)
{
  const int t = threadIdx.x, w = t >> 6, l = t & 63;
  const int m = l & 15, quad = l >> 4;
  const int bm = blockIdx.y * 128 + (w >> 1) * 64;
  const int bn = blockIdx.x * 128 + (w & 1) * 64;
  f32x4 acc[4][4] = {};
  const unsigned short* Ab = A + (size_t)(bm + m) * KAUG;
  const unsigned short* Wb = W + (size_t)(bn + m) * KAUG;
  for (int kk = 0; kk < KAUG; kk += 32) {
    bf16x8 af[4], bf[4];
#pragma unroll
    for (int i = 0; i < 4; ++i) af[i] = *(const bf16x8*)(Ab + (size_t)i * 16 * KAUG + kk + quad * 8);
#pragma unroll
    for (int j = 0; j < 4; ++j) bf[j] = *(const bf16x8*)(Wb + (size_t)j * 16 * KAUG + kk + quad * 8);
#pragma unroll
    for (int i = 0; i < 4; ++i)
#pragma unroll
      for (int j = 0; j < 4; ++j)
        acc[i][j] = __builtin_amdgcn_mfma_f32_16x16x32_bf16(af[i], bf[j], acc[i][j], 0, 0, 0);
  }

  float bj[4];
#pragma unroll
  for (int j = 0; j < 4; ++j) bj[j] = bias[bn + j * 16 + m];

  if (mode == 2) {
#pragma unroll
    for (int i = 0; i < 4; ++i)
#pragma unroll
      for (int r = 0; r < 4; ++r) {
        int row = bm + i * 16 + quad * 4 + r;
#pragma unroll
        for (int j = 0; j < 4; ++j)
          dst[(size_t)row * 768 + bn + j * 16 + m] = acc[i][j][r] + bj[j];
      }
    return;
  }
  int g = (blockIdx.x * 128) / DIMc;           // uniform per block
#pragma unroll
  for (int j = 0; j < 4; ++j) {
    int col = bn + j * 16 + m;
    int jj = col - g * DIMc, hh = jj >> 6, d = jj & 63;
#pragma unroll
    for (int i = 0; i < 4; ++i)
#pragma unroll
      for (int r = 0; r < 4; ++r) {
        int row = bm + i * 16 + quad * 4 + r;
        int bb = row / NNtok, tt = row % NNtok;
        float v = acc[i][j][r] + bj[j];
        if (g == 0) {
          qh[((size_t)(bb * Hh + hh) * NNtok + tt) * Dd + d] = bf16_1(v * 0.125f);
        } else if (g == 1) {
          kfh[((size_t)(bb * Hh + hh) * 2560 + 1280 + tt) * Dd + d] = bf16_1(v);
          if (tt < 256) kmid[((size_t)(bb * Hh + hh) * 256 + tt) * Dd + d] = v;
        } else {
          vb[((size_t)(bb * Hh + hh) * NNtok + tt) * Dd + d] = v;
        }
      }
  }
}

// ---------------- fp32 GEMM for ID_V ----------------
__global__ __launch_bounds__(256) void gemm_idv(
    const float* __restrict__ A, const float* __restrict__ W,
    const float* __restrict__ bias, const float* __restrict__ low,
    const float* __restrict__ Bl, float* __restrict__ dst)
{
  __shared__ alignas(16) float As[16][68];
  __shared__ alignas(16) float Bs[16][68];
  const int t  = threadIdx.x;
  const int tx = t & 15, ty = t >> 4;
  const int bn = blockIdx.x * 64, bm = blockIdx.y * 64;
  const int am = t >> 2, ak = (t & 3) << 2;
  float acc[4][4] = {};
  for (int k0 = 0; k0 < 768; k0 += 16) {
    float4 av = *(const float4*)(A + (size_t)(bm + am) * 768 + k0 + ak);
    float4 bv = *(const float4*)(W + (size_t)(bn + am) * 768 + k0 + ak);
    As[ak + 0][am] = av.x; As[ak + 1][am] = av.y; As[ak + 2][am] = av.z; As[ak + 3][am] = av.w;
    Bs[ak + 0][am] = bv.x; Bs[ak + 1][am] = bv.y; Bs[ak + 2][am] = bv.z; Bs[ak + 3][am] = bv.w;
    __syncthreads();
#pragma unroll
    for (int kk = 0; kk < 16; ++kk) {
      float4 a4 = *(const float4*)&As[kk][ty << 2];
      float4 b4 = *(const float4*)&Bs[kk][tx << 2];
      float ar[4] = { a4.x, a4.y, a4.z, a4.w };
      float br[4] = { b4.x, b4.y, b4.z, b4.w };
#pragma unroll
      for (int i = 0; i < 4; ++i)
#pragma unroll
        for (int j = 0; j < 4; ++j) acc[i][j] += ar[i] * br[j];
    }
    __syncthreads();
  }
#pragma unroll
  for (int i = 0; i < 4; ++i) {
    int mg = bm + (ty << 2) + i;
#pragma unroll
    for (int j = 0; j < 4; ++j) {
      int col = bn + (tx << 2) + j;
      float v = acc[i][j] + bias[col];
      float lo = 0.f;
#pragma unroll
      for (int r = 0; r < 8; ++r) lo += low[(size_t)mg * 8 + r] * Bl[(size_t)col * 8 + r];
      dst[(size_t)mg * 768 + col] = v + lo * 0.125f;
    }
  }
}

// ---------------- radix helper: select bin from per-wave 256-bin hist ----------------
__device__ __forceinline__ void radix_sel(
    unsigned int* hist, int l, int& kk, int& ceq, unsigned int& bin)
{
  unsigned int h0 = hist[4 * l + 0], h1 = hist[4 * l + 1],
               h2 = hist[4 * l + 2], h3 = hist[4 * l + 3];
  unsigned int s3 = h3, s2 = h2 + s3, s1 = h1 + s2, s0 = h0 + s1;
  unsigned int tsum = s0;
#pragma unroll
  for (int off = 1; off < 64; off <<= 1) {
    unsigned int other = __shfl(tsum, l + off, 64);
    tsum += (l + off < 64) ? other : 0u;
  }
  unsigned int T = tsum - s0;   // suffix over lanes > l
  unsigned int Sv0 = T + s0, Sv1 = T + s1, Sv2 = T + s2, Sv3 = T + s3, Sv4 = T;
  int fb = -1, fkk = 0, fceq = 0;
  unsigned int ukk = (unsigned int)kk;
  if (Sv0 >= ukk && Sv1 < ukk) { fb = 4 * l + 0; fkk = (int)(ukk - Sv1); fceq = (int)(Sv0 - Sv1); }
  if (Sv1 >= ukk && Sv2 < ukk) { fb = 4 * l + 1; fkk = (int)(ukk - Sv2); fceq = (int)(Sv1 - Sv2); }
  if (Sv2 >= ukk && Sv3 < ukk) { fb = 4 * l + 2; fkk = (int)(ukk - Sv3); fceq = (int)(Sv2 - Sv3); }
  if (Sv3 >= ukk && Sv4 < ukk) { fb = 4 * l + 3; fkk = (int)(ukk - Sv4); fceq = (int)(Sv3 - Sv4); }
  unsigned long long mb = __ballot(fb >= 0);
  int src = __ffsll(mb) - 1;
  bin = (unsigned int)__shfl(fb, src, 64);
  kk  = __shfl(fkk, src, 64);
  ceq = __shfl(fceq, src, 64);
}

// ---------------- MFMA top-k attention v6: 16 q-rows per block (quarter K/V traffic) ----------------
// Phase A: QK^T with the FULL 16-row A-fragment; grouped 4-deep prefetch.
// Phase B/C: wave w radix-selects rows 4w..4w+3 serially (2-stage radix).
// Phase D: PV with full 16-row weight A-fragment; grouped prefetch.
// LDS ~86.6 KB -> 1 block/CU for NK=2560 (gfx950: 160 KB addressable LDS).
template<int NK, int MINW>
__global__ __launch_bounds__(256, MINW) void attn_mfma6(
    const unsigned short* __restrict__ qh,   // (bh,1280,64) bf16
    const unsigned short* __restrict__ kf,   // (bh,NK,64)   bf16
    const unsigned short* __restrict__ vt,   // (bh,64,NK)   bf16 (V^T)
    int TK, int qrow0, float* __restrict__ xo, int nofs)
{
  constexpr int SCP = NK + 8;          // pad 8 shorts -> row stride 1284 words (bank stagger)
  constexpr int W = NK / 128;          // score words per lane per row
  __shared__ alignas(16) unsigned short sc16[16][SCP];
  __shared__ unsigned int hist4[4][256];
  __shared__ float wavemax[4][16];
  __shared__ float rowinv[16];

  const int t = threadIdx.x, w = t >> 6, l = t & 63;
  const int bh = blockIdx.x % NBH;
  const int rb = blockIdx.x / NBH;
  const int b = bh / Hh, h = bh % Hh;
  const int qbase = qrow0 + rb * 16;
  const int m = l & 15, quad = l >> 4;

  // ---- Phase A: QK^T via MFMA (A rows 0-15 = q), grouped 4-deep prefetch ----
  bf16x8 aq0, aq1;
  {
    const unsigned short* qp = qh + ((size_t)bh * NNtok + qbase + m) * Dd + quad * 8;
    aq0 = *(const bf16x8*)qp;
    aq1 = *(const bf16x8*)(qp + 32);
  }
  float mx[4] = { -3.0e38f, -3.0e38f, -3.0e38f, -3.0e38f };  // rows quad*4+r
  constexpr int ITA = NK / 64;
  constexpr int GA = (ITA >= 4) ? 4 : ITA;
  const unsigned short* kpA = kf + (size_t)bh * NK * Dd + (size_t)(w * 16 + m) * Dd + quad * 8;
  bf16x8 kbuf[2][GA][2];
#pragma unroll
  for (int i = 0; i < GA; ++i) {
    kbuf[0][i][0] = *(const bf16x8*)(kpA + (size_t)i * 64 * Dd);
    kbuf[0][i][1] = *(const bf16x8*)(kpA + (size_t)i * 64 * Dd + 32);
  }
  int abuf = 0;
  for (int g0 = 0; g0 < ITA; g0 += GA) {
    if (g0 + GA < ITA) {
#pragma unroll
      for (int i = 0; i < GA; ++i) {
        kbuf[1 - abuf][i][0] = *(const bf16x8*)(kpA + (size_t)(g0 + GA + i) * 64 * Dd);
        kbuf[1 - abuf][i][1] = *(const bf16x8*)(kpA + (size_t)(g0 + GA + i) * 64 * Dd + 32);
      }
    }
#pragma unroll
    for (int i = 0; i < GA; ++i) {
      int n0 = w * 16 + (g0 + i) * 64;
      f32x4 acc = {0.f, 0.f, 0.f, 0.f};
      acc = __builtin_amdgcn_mfma_f32_16x16x32_bf16(aq0, kbuf[abuf][i][0], acc, 0, 0, 0);
      acc = __builtin_amdgcn_mfma_f32_16x16x32_bf16(aq1, kbuf[abuf][i][1], acc, 0, 0, 0);
#pragma unroll
      for (int r = 0; r < 4; ++r) {
        float v = acc[r];
        mx[r] = fmaxf(mx[r], v);
        sc16[quad * 4 + r][n0 + m] = bf16_1(v);
      }
    }
    abuf ^= 1;
  }
  // max over the 16 lanes of each quad (cols); wavemax[w][row]
#pragma unroll
  for (int off = 1; off < 16; off <<= 1)
#pragma unroll
    for (int r = 0; r < 4; ++r) mx[r] = fmaxf(mx[r], __shfl_xor(mx[r], off, 64));
  if (m == 0) {
#pragma unroll
    for (int r = 0; r < 4; ++r) wavemax[w][quad * 4 + r] = mx[r];
  }
  __syncthreads();

  // ---- Phase B/C: wave w selects rows 4w..4w+3 (serial, 2-stage radix) ----
  for (int sub = 0; sub < 4; ++sub) {
    const int row = w * 4 + sub;
    unsigned int* sp = (unsigned int*)&sc16[row][0];
    unsigned int kw[W];
#pragma unroll
    for (int j = 0; j < W; ++j) {
      unsigned int v = sp[j * 64 + l];
      unsigned int mm = ((v >> 15) & 0x00010001u) * 0x7fffu + 0x80008000u;
      kw[j] = v ^ mm;   // bf16 -> monotone u16, both halves
    }
    // stage 1: bit-plane on bits 15..8
    unsigned int prefix = 0;
    int kk = TK;
#pragma unroll 1
    for (int bit = 15; bit >= 8; --bit) {
      unsigned int hmask = (0xFFFFu << bit) & 0xFFFFu;
      unsigned int cand  = prefix | (1u << bit);
      int cnt = 0;
#pragma unroll
      for (int j = 0; j < W; ++j) {
        unsigned int k2 = kw[j];
        cnt += __popcll(__ballot((k2 & hmask) == cand));
        cnt += __popcll(__ballot(((k2 >> 16) & hmask) == cand));
      }
      if (cnt >= kk) prefix = cand; else kk -= cnt;
    }
    // stage 2: per-wave histogram of low byte among prefix-matching candidates
    unsigned int* hist = hist4[w];
#pragma unroll
    for (int z = 0; z < 4; ++z) hist[l + z * 64] = 0u;
    const unsigned int pfx8 = prefix >> 8;
#pragma unroll
    for (int j = 0; j < W; ++j) {
      unsigned int k2 = kw[j];
      unsigned int lo = k2 & 0xFFFFu, hi = k2 >> 16;
      if ((lo >> 8) == pfx8) atomicAdd(&hist[lo & 255u], 1u);
      if ((hi >> 8) == pfx8) atomicAdd(&hist[hi & 255u], 1u);
    }
    unsigned int b2;
    int ceq = 0;
    radix_sel(hist, l, kk, ceq, b2);
    const unsigned int Tkey = prefix | b2;
    const int need = kk;
    if (need < ceq) {   // ties at threshold: keep lowest indices (jax order)
      int seen = 0;
      unsigned long long below = (1ull << l) - 1ull;
#pragma unroll
      for (int j = 0; j < W; ++j) {
        unsigned int k2 = kw[j];
        bool eq0 = ((k2 & 0xFFFFu) == Tkey);
        bool eq1 = ((k2 >> 16) == Tkey);
        unsigned long long m0 = __ballot(eq0), m1 = __ballot(eq1);
        int bfr = __popcll(m0 & below) + __popcll(m1 & below);
        if (eq0 && (seen + bfr) >= need) kw[j] &= 0xFFFF0000u;
        if (eq1 && (seen + bfr + (eq0 ? 1 : 0)) >= need) kw[j] &= 0x0000FFFFu;
        seen += __popcll(m0) + __popcll(m1);
      }
    }
    // exp over selected, bf16 weights back in place
    float rm = fmaxf(fmaxf(wavemax[0][row], wavemax[1][row]),
                     fmaxf(wavemax[2][row], wavemax[3][row]));
    float sum = 0.f;
#pragma unroll
    for (int j = 0; j < W; ++j) {
      unsigned int k2 = kw[j];
      unsigned int lo = k2 & 0xFFFFu, hi = k2 >> 16;
      unsigned int mm = ((~k2 >> 15) & 0x00010001u) * 0x7fffu + 0x80008000u;
      unsigned int o2 = k2 ^ mm;   // back to bf16 bits
      float v0 = bf2f(o2 & 0xFFFFu);
      float v1 = bf2f(o2 >> 16);
      float w0 = (lo >= Tkey) ? __expf(v0 - rm) : 0.f;
      float w1 = (hi >= Tkey) ? __expf(v1 - rm) : 0.f;
      sp[j * 64 + l] = pk_bf16(w0, w1);
      sum += w0 + w1;
    }
#pragma unroll
    for (int off = 32; off; off >>= 1) sum += __shfl_xor(sum, off, 64);
    if (l == 0) rowinv[row] = 1.f / sum;
  }
  __syncthreads();

  // ---- Phase D: PV via MFMA (A rows 0-15 = weights), grouped prefetch ----
  constexpr int ITD = NK / 32;
  constexpr int GD = (ITD >= 4) ? 4 : ITD;
  const unsigned short* vrow = vt + (size_t)bh * Dd * NK + (size_t)(w * 16 + m) * NK + quad * 8;
  f32x4 o = {0.f, 0.f, 0.f, 0.f};
  bf16x8 vbuf[2][GD], wbuf[2][GD];
#pragma unroll
  for (int i = 0; i < GD; ++i) {
    vbuf[0][i] = *(const bf16x8*)(vrow + i * 32);
    wbuf[0][i] = *(const bf16x8*)&sc16[m][i * 32 + quad * 8];
  }
  int dbuf = 0;
  for (int g0 = 0; g0 < ITD; g0 += GD) {
    if (g0 + GD < ITD) {
#pragma unroll
      for (int i = 0; i < GD; ++i) {
        vbuf[1 - dbuf][i] = *(const bf16x8*)(vrow + (g0 + GD + i) * 32);
        wbuf[1 - dbuf][i] = *(const bf16x8*)&sc16[m][(g0 + GD + i) * 32 + quad * 8];
      }
    }
#pragma unroll
    for (int i = 0; i < GD; ++i)
      o = __builtin_amdgcn_mfma_f32_16x16x32_bf16(wbuf[dbuf][i], vbuf[dbuf][i], o, 0, 0, 0);
    dbuf ^= 1;
  }
#pragma unroll
  for (int r = 0; r < 4; ++r) {
    int row = quad * 4 + r;
    int n = nofs + rb * 16 + row;
    xo[((size_t)b * NNtok + n) * DIMc + h * 64 + w * 16 + m] = o[r] * rowinv[row];
  }
}

// ---------------- host ----------------
extern "C" void kernel_launch(void* const* d_in, const int* in_sizes, int n_in,
                              void* d_out, int out_size, void* d_ws, size_t ws_size,
                              hipStream_t stream)
{
  const float* x       = (const float*)d_in[0];
  const float* id_tot  = (const float*)d_in[1];
  const float* mem_k   = (const float*)d_in[2];
  const float* mem_v   = (const float*)d_in[3];
  const float* W_qkv   = (const float*)d_in[4];
  const float* b_qkv   = (const float*)d_in[5];
  const float* qkv_A   = (const float*)d_in[6];
  const float* qkv_B   = (const float*)d_in[7];
  const float* W_proj  = (const float*)d_in[8];
  const float* b_proj  = (const float*)d_in[9];
  const float* route_W = (const float*)d_in[10];
  const float* proj_A  = (const float*)d_in[11];
  const float* proj_B  = (const float*)d_in[12];
  const float* W_idk   = (const float*)d_in[13];
  const float* b_idk   = (const float*)d_in[14];
  const float* idk_A   = (const float*)d_in[15];
  const float* idk_B   = (const float*)d_in[16];
  const float* W_idv   = (const float*)d_in[17];
  const float* b_idv   = (const float*)d_in[18];
  const float* idv_A   = (const float*)d_in[19];
  const float* idv_B   = (const float*)d_in[20];

  float* ws   = (float*)d_ws;
  float* vb   = ws + OVb;
  float* xo   = ws + OXO;
  float* qlow = ws + OQL;
  float* IDK  = ws + OIDK;
  float* IDV  = ws + OIDV;
  float* lowk = ws + OLK;
  float* lowv = ws + OLV;
  float* rd   = ws + ORD;
  float* plow = ws + OPL;
  unsigned short* qh   = (unsigned short*)(ws + OQH);
  unsigned short* kfh  = (unsigned short*)(ws + OKFH);
  unsigned short* vth  = (unsigned short*)(ws + OVTH);
  unsigned short* kmh  = (unsigned short*)(ws + OKMH);
  unsigned short* vmth = (unsigned short*)(ws + OVMTH);
  unsigned short* Aa   = (unsigned short*)(ws + OAa);
  unsigned short* Wa   = (unsigned short*)(ws + OWa);
  unsigned short* Wa2  = (unsigned short*)(ws + OWa2);

  float* out  = (float*)d_out;
  float* kmid = out + KMID_OFF;
  float* vmid = out + VMID_OFF;

  // staging: mem_k cast, mem_v transpose, both W_aug builds — one launch
  prep<<<7680, 256, 0, stream>>>(mem_k, mem_v, W_qkv, qkv_B, W_proj, proj_B,
                                 kfh, vth, Wa, Wa2);

  // LoRA downs
  dot_small<<<1280, 256, 0, stream>>>(x, qkv_A, qlow, 24);
  dot_id<<<256, 256, 0, stream>>>(id_tot, idk_A, idv_A, lowk, lowv);

  // QKV via MFMA with augmented K (fused LoRA)
  cast_pack<<<2000, 256, 0, stream>>>(x, qlow, Aa, 24);
  gemm_mfma<<<dim3(18, 40), 256, 0, stream>>>(Aa, Wa, b_qkv, 0, nullptr,
                                              qh, kmid, vb, kfh);
  // ID_V (fp32), ID_K
  gemm_idv<<<dim3(12, 16), 256, 0, stream>>>(id_tot, W_idv, b_idv, lowv, idv_B, IDV);
  idk_kernel<<<256, 256, 0, stream>>>(id_tot, W_idk, b_idk, lowk, idk_B, IDK);
  // outputs k_m_id / v_m_id; vb rows 0-255 updated in place
  fixup_kernel<<<3072, 256, 0, stream>>>(vb, IDK, IDV, kmid, vmid, kmh);

  // V^T bf16 staging (post-fixup)
  transpose_post<<<1152, 256, 0, stream>>>(vb, vth, vmth);

  // attention: 16 rows/block (XCD-swizzled: blockIdx = rb*48 + bh)
  attn_mfma6<256, 4><<<768, 256, 0, stream>>>(qh, kmh, vmth, 128, 0, xo, 0);
  attn_mfma6<2560, 1><<<3072, 256, 0, stream>>>(qh, kfh, vth, 640, 256, xo, 256);

  // routed output projection
  dot_rp<<<1280, 256, 0, stream>>>(xo, route_W, proj_A, rd, plow);
  cast_pack_proj<<<2000, 256, 0, stream>>>(xo, rd, plow, Aa);
  gemm_mfma<<<dim3(6, 40), 256, 0, stream>>>(Aa, Wa2, b_proj, 2, out,
                                             nullptr, nullptr, nullptr, nullptr);
}

// Round 10
// 900.432 us; speedup vs baseline: 1.2587x; 1.2587x over previous
//
#include <hip/hip_runtime.h>
#include <cstddef>

// ---------------- problem constants ----------------
#define Bq    4
#define Hh    12
#define Dd    64
#define NNtok 1280
#define DIMc  768
#define KAUG  800      // 768 + 32 augmented-K for fused LoRA
#define NBH   48       // Bq*Hh

typedef __attribute__((ext_vector_type(8))) short bf16x8;
typedef __attribute__((ext_vector_type(4))) float f32x4;

// workspace offsets (floats)
static const size_t OVb   = 0;                   // vb fp32 (B,H,1280,64); rows 0-255 -> v_add_id
static const size_t OXO   = 3932160;             // xo fp32 (B,1280,768)
static const size_t OQL   = 7864320;             // qkv low (5120,24)
static const size_t OIDK  = 7987200;             // 1+tanh(ID_K) (1024,12)
static const size_t OIDV  = 7999488;             // ID_V (1024,768)
static const size_t OLK   = 8785920;             // id_lowk (1024,8)
static const size_t OLV   = 8794112;             // id_lowv (1024,8)
static const size_t ORD   = 8802304;             // route dots (5120,4)
static const size_t OPL   = 8822784;             // proj low (5120,32)
static const size_t OQH   = 8986624;             // qh bf16 (B,H,1280,64)
static const size_t OKFH  = 10952704;            // kfh bf16 (B,H,2560,64) [mem_k|k]
static const size_t OVTH  = 14884864;            // vth bf16 (B,H,64,2560)
static const size_t OKMH  = 18817024;            // kmh bf16 (B,H,256,64)
static const size_t OVMTH = 19210240;            // vmth bf16 (B,H,64,256)
static const size_t OAa   = 19603456;            // A_aug bf16 (5120,800)
static const size_t OWa   = 21651456;            // W_aug qkv bf16 (2304,800)
static const size_t OWa2  = 22573056;            // W_aug proj bf16 (768,800)

// d_out offsets (floats)
static const size_t KMID_OFF = 3932160;
static const size_t VMID_OFF = 4718592;

__device__ __forceinline__ unsigned int pk_bf16(float a, float b) {  // RNE pack
  unsigned int ua = __float_as_uint(a), ub = __float_as_uint(b);
  ua += 0x7fffu + ((ua >> 16) & 1u);
  ub += 0x7fffu + ((ub >> 16) & 1u);
  return (ua >> 16) | (ub & 0xffff0000u);
}
__device__ __forceinline__ unsigned short bf16_1(float a) {
  unsigned int ua = __float_as_uint(a);
  ua += 0x7fffu + ((ua >> 16) & 1u);
  return (unsigned short)(ua >> 16);
}
__device__ __forceinline__ float bf2f(unsigned int h) {
  return __uint_as_float(h << 16);
}

// ---------------- prep: cast_k | transpose(mem_v) | cast_w_qkv | cast_w_proj ----------------
__global__ __launch_bounds__(256) void prep(
    const float* __restrict__ mem_k, const float* __restrict__ mem_v,
    const float* __restrict__ W_qkv, const float* __restrict__ qkvB,
    const float* __restrict__ W_proj, const float* __restrict__ projB,
    unsigned short* __restrict__ kfh, unsigned short* __restrict__ vth,
    unsigned short* __restrict__ Wa, unsigned short* __restrict__ Wa2)
{
  __shared__ float tl[64][65];
  const int blk = blockIdx.x, t = threadIdx.x;
  if (blk < 1920) {                       // cast mem_k -> kfh rows 0..1279
    size_t idx = ((size_t)blk * 256 + t) * 8;
    int bh = (int)(idx / 81920);
    int r  = (int)(idx % 81920);
    const float* s = mem_k + (size_t)bh * 81920 + r;
    float4 a = *(const float4*)s;
    float4 b = *(const float4*)(s + 4);
    unsigned int* dp = (unsigned int*)(kfh + (size_t)bh * 163840 + r);
    dp[0] = pk_bf16(a.x, a.y); dp[1] = pk_bf16(a.z, a.w);
    dp[2] = pk_bf16(b.x, b.y); dp[3] = pk_bf16(b.z, b.w);
  } else if (blk < 2880) {                // transpose mem_v -> vth cols 0..1279
    int b2 = blk - 1920;
    int bh = b2 / 20, t0 = (b2 % 20) * 64;
    const float* sb = mem_v + (size_t)bh * 81920 + (size_t)t0 * 64;
#pragma unroll
    for (int p = 0; p < 4; ++p) {
      int flat = p * 256 + t;
      int r = flat >> 4, c4 = (flat & 15) << 2;
      float4 v = *(const float4*)(sb + r * 64 + c4);
      tl[r][c4 + 0] = v.x; tl[r][c4 + 1] = v.y;
      tl[r][c4 + 2] = v.z; tl[r][c4 + 3] = v.w;
    }
    __syncthreads();
    unsigned short* db = vth + (size_t)bh * 163840 + t0;
#pragma unroll
    for (int p = 0; p < 8; ++p) {
      int flat = p * 256 + t;
      int d = flat >> 5, u = flat & 31;
      *(unsigned int*)(db + (size_t)d * 2560 + 2 * u) = pk_bf16(tl[2 * u][d], tl[2 * u + 1][d]);
    }
  } else if (blk < 6480) {                // W_aug qkv
    int idx = (blk - 2880) * 256 + t;     // 2304*400 uint pairs
    int row = idx / 400, c = (idx % 400) * 2;
    float a, b;
    if (c < 768) {
      a = W_qkv[(size_t)row * 768 + c]; b = W_qkv[(size_t)row * 768 + c + 1];
    } else {
      int g = row / 768, jj = row % 768;
      int e0 = c - 768, e1 = e0 + 1;
      a = (e0 < 24 && (e0 >> 3) == g) ? qkvB[(size_t)g * 6144 + jj * 8 + (e0 & 7)] * 0.125f : 0.f;
      b = (e1 < 24 && (e1 >> 3) == g) ? qkvB[(size_t)g * 6144 + jj * 8 + (e1 & 7)] * 0.125f : 0.f;
    }
    *(unsigned int*)(Wa + (size_t)row * KAUG + c) = pk_bf16(a, b);
  } else {                                // W_aug proj
    int idx = (blk - 6480) * 256 + t;     // 768*400
    int row = idx / 400, c = (idx % 400) * 2;
    float a, b;
    if (c < 768) {
      a = W_proj[(size_t)row * 768 + c]; b = W_proj[(size_t)row * 768 + c + 1];
    } else {
      int e0 = c - 768, e1 = e0 + 1;
      a = projB[(size_t)(e0 >> 3) * 6144 + row * 8 + (e0 & 7)];
      b = projB[(size_t)(e1 >> 3) * 6144 + row * 8 + (e1 & 7)];
    }
    *(unsigned int*)(Wa2 + (size_t)row * KAUG + c) = pk_bf16(a, b);
  }
}

// ---------------- small row-dot kernel ----------------
__global__ __launch_bounds__(256) void dot_small(
    const float* __restrict__ src, const float* __restrict__ mat,
    float* __restrict__ dst, int nout)
{
  int wv = threadIdx.x >> 6, ln = threadIdx.x & 63;
  size_t row = (size_t)blockIdx.x * 4 + wv;
  const float* s = src + row * DIMc;
  for (int o = 0; o < nout; ++o) {
    float p = 0.f;
    const float* m = mat + (size_t)o * DIMc;
    for (int c = ln; c < DIMc; c += 64) p += s[c] * m[c];
    for (int off = 32; off; off >>= 1) p += __shfl_xor(p, off, 64);
    if (ln == 0) dst[row * nout + o] = p;
  }
}

// ---------------- fused id lora downs: lowk(8) + lowv(8) ----------------
__global__ __launch_bounds__(256) void dot_id(
    const float* __restrict__ id_tot, const float* __restrict__ idkA,
    const float* __restrict__ idvA, float* __restrict__ lowk,
    float* __restrict__ lowv)
{
  int wv = threadIdx.x >> 6, ln = threadIdx.x & 63;
  size_t row = (size_t)blockIdx.x * 4 + wv;
  const float* s = id_tot + row * DIMc;
  for (int o = 0; o < 8; ++o) {
    float p = 0.f, q = 0.f;
    const float* m1 = idkA + (size_t)o * DIMc;
    const float* m2 = idvA + (size_t)o * DIMc;
    for (int c = ln; c < DIMc; c += 64) { p += s[c] * m1[c]; q += s[c] * m2[c]; }
    for (int off = 32; off; off >>= 1) { p += __shfl_xor(p, off, 64); q += __shfl_xor(q, off, 64); }
    if (ln == 0) { lowk[row * 8 + o] = p; lowv[row * 8 + o] = q; }
  }
}

// ---------------- fused route+plow dots ----------------
__global__ __launch_bounds__(256) void dot_rp(
    const float* __restrict__ xo, const float* __restrict__ routeW,
    const float* __restrict__ projA, float* __restrict__ rd,
    float* __restrict__ plow)
{
  int wv = threadIdx.x >> 6, ln = threadIdx.x & 63;
  size_t row = (size_t)blockIdx.x * 4 + wv;
  const float* s = xo + row * DIMc;
  float xr[12];
#pragma unroll
  for (int i = 0; i < 12; ++i) xr[i] = s[ln + i * 64];
  for (int o = 0; o < 4; ++o) {
    float p = 0.f;
    const float* m = routeW + (size_t)o * DIMc;
#pragma unroll
    for (int i = 0; i < 12; ++i) p += xr[i] * m[ln + i * 64];
    for (int off = 32; off; off >>= 1) p += __shfl_xor(p, off, 64);
    if (ln == 0) rd[row * 4 + o] = p;
  }
  for (int o = 0; o < 32; ++o) {
    float p = 0.f;
    const float* m = projA + (size_t)o * DIMc;
#pragma unroll
    for (int i = 0; i < 12; ++i) p += xr[i] * m[ln + i * 64];
    for (int off = 32; off; off >>= 1) p += __shfl_xor(p, off, 64);
    if (ln == 0) plow[row * 32 + o] = p;
  }
}

// ---------------- merged: gemm_idv (blocks 0..191) | idk (blocks 192..447) ----------------
__global__ __launch_bounds__(256) void idv_idk(
    const float* __restrict__ id_tot,
    const float* __restrict__ W_idv, const float* __restrict__ b_idv,
    const float* __restrict__ lowv, const float* __restrict__ idv_B,
    float* __restrict__ IDV,
    const float* __restrict__ W_idk, const float* __restrict__ b_idk,
    const float* __restrict__ lowk, const float* __restrict__ idk_B,
    float* __restrict__ IDK)
{
  __shared__ alignas(16) float As[16][68];
  __shared__ alignas(16) float Bs[16][68];
  const int blk = blockIdx.x, t = threadIdx.x;
  if (blk < 192) {   // ID_V fp32 GEMM, 12x16 tile grid
    const int tx = t & 15, ty = t >> 4;
    const int bn = (blk % 12) * 64, bm = (blk / 12) * 64;
    const int am = t >> 2, ak = (t & 3) << 2;
    float acc[4][4] = {};
    for (int k0 = 0; k0 < 768; k0 += 16) {
      float4 av = *(const float4*)(id_tot + (size_t)(bm + am) * 768 + k0 + ak);
      float4 bv = *(const float4*)(W_idv + (size_t)(bn + am) * 768 + k0 + ak);
      As[ak + 0][am] = av.x; As[ak + 1][am] = av.y; As[ak + 2][am] = av.z; As[ak + 3][am] = av.w;
      Bs[ak + 0][am] = bv.x; Bs[ak + 1][am] = bv.y; Bs[ak + 2][am] = bv.z; Bs[ak + 3][am] = bv.w;
      __syncthreads();
#pragma unroll
      for (int kk = 0; kk < 16; ++kk) {
        float4 a4 = *(const float4*)&As[kk][ty << 2];
        float4 b4 = *(const float4*)&Bs[kk][tx << 2];
        float ar[4] = { a4.x, a4.y, a4.z, a4.w };
        float br[4] = { b4.x, b4.y, b4.z, b4.w };
#pragma unroll
        for (int i = 0; i < 4; ++i)
#pragma unroll
          for (int j = 0; j < 4; ++j) acc[i][j] += ar[i] * br[j];
      }
      __syncthreads();
    }
#pragma unroll
    for (int i = 0; i < 4; ++i) {
      int mg = bm + (ty << 2) + i;
#pragma unroll
      for (int j = 0; j < 4; ++j) {
        int col = bn + (tx << 2) + j;
        float v = acc[i][j] + b_idv[col];
        float lo = 0.f;
#pragma unroll
        for (int r = 0; r < 8; ++r) lo += lowv[(size_t)mg * 8 + r] * idv_B[(size_t)col * 8 + r];
        IDV[(size_t)mg * 768 + col] = v + lo * 0.125f;
      }
    }
  } else {           // ID_K: 1+tanh
    int wv = t >> 6, ln = t & 63;
    size_t row = (size_t)(blk - 192) * 4 + wv;
    const float* s = id_tot + row * DIMc;
    for (int h = 0; h < Hh; ++h) {
      float p = 0.f;
      const float* m = W_idk + (size_t)h * DIMc;
      for (int c = ln; c < DIMc; c += 64) p += s[c] * m[c];
      for (int off = 32; off; off >>= 1) p += __shfl_xor(p, off, 64);
      if (ln == 0) {
        float lo = 0.f;
        for (int r = 0; r < 8; ++r) lo += lowk[row * 8 + r] * idk_B[h * 8 + r];
        IDK[row * Hh + h] = 1.f + tanhf(p + b_idk[h] + lo * 0.125f);
      }
    }
  }
}

// ---------------- fixup: kmid holds raw k; multiply by IDK in place; v add IDV ----------------
__global__ __launch_bounds__(256) void fixup_kernel(
    float* __restrict__ vb, const float* __restrict__ IDK,
    const float* __restrict__ IDV, float* __restrict__ kmid,
    float* __restrict__ vmid, unsigned short* __restrict__ kmh)
{
  int e = blockIdx.x * 256 + threadIdx.x;   // flat (b,h,tt,d), tt<256
  int d  = e & 63;
  int r1 = e >> 6;
  int tt = r1 & 255;
  int r2 = r1 >> 8;
  int h  = r2 % Hh;
  int b  = r2 / Hh;
  float km = kmid[e] * IDK[(size_t)(b * 256 + tt) * Hh + h];
  kmid[e] = km;
  kmh[e] = bf16_1(km);
  size_t src = ((size_t)(b * Hh + h) * NNtok + tt) * Dd + d;
  float vv = vb[src] + IDV[(size_t)(b * 256 + tt) * DIMc + h * 64 + d];
  vb[src] = vv;
  vmid[e] = vv;
}

// ---------------- post-fixup transposes ----------------
__global__ __launch_bounds__(256) void transpose_post(
    const float* __restrict__ vb, unsigned short* __restrict__ vth,
    unsigned short* __restrict__ vmth)
{
  __shared__ float tl[64][65];
  const int blk = blockIdx.x, t = threadIdx.x;
  int bh, t0, dstCols, colOfs;
  unsigned short* dstp;
  size_t dstBh;
  if (blk < 960) { bh = blk / 20; t0 = (blk % 20) * 64; dstp = vth; dstBh = 163840; dstCols = 2560; colOfs = 1280; }
  else { int b2 = blk - 960; bh = b2 / 4; t0 = (b2 % 4) * 64; dstp = vmth; dstBh = 16384; dstCols = 256; colOfs = 0; }
  const float* sb = vb + (size_t)bh * 81920 + (size_t)t0 * 64;
#pragma unroll
  for (int p = 0; p < 4; ++p) {
    int flat = p * 256 + t;
    int r = flat >> 4, c4 = (flat & 15) << 2;
    float4 v = *(const float4*)(sb + r * 64 + c4);
    tl[r][c4 + 0] = v.x; tl[r][c4 + 1] = v.y;
    tl[r][c4 + 2] = v.z; tl[r][c4 + 3] = v.w;
  }
  __syncthreads();
  unsigned short* db = dstp + (size_t)bh * dstBh + colOfs + t0;
#pragma unroll
  for (int p = 0; p < 8; ++p) {
    int flat = p * 256 + t;
    int d = flat >> 5, u = flat & 31;
    *(unsigned int*)(db + (size_t)d * dstCols + 2 * u) = pk_bf16(tl[2 * u][d], tl[2 * u + 1][d]);
  }
}

// ---------------- pack A_aug for qkv ----------------
__global__ __launch_bounds__(256) void cast_pack(
    const float* __restrict__ mainp, const float* __restrict__ extra,
    unsigned short* __restrict__ dst, int extraN)
{
  int idx = blockIdx.x * 256 + threadIdx.x;    // 5120*100 groups of 8
  int row = idx / 100, c8 = (idx % 100) * 8;
  unsigned int w[4];
  if (c8 < 768) {
    const float* s = mainp + (size_t)row * 768 + c8;
    float4 a = *(const float4*)s;
    float4 b = *(const float4*)(s + 4);
    w[0] = pk_bf16(a.x, a.y); w[1] = pk_bf16(a.z, a.w);
    w[2] = pk_bf16(b.x, b.y); w[3] = pk_bf16(b.z, b.w);
  } else {
    float v[8];
#pragma unroll
    for (int j = 0; j < 8; ++j) {
      int e = c8 - 768 + j;
      v[j] = (e < extraN) ? extra[(size_t)row * extraN + e] : 0.f;
    }
    w[0] = pk_bf16(v[0], v[1]); w[1] = pk_bf16(v[2], v[3]);
    w[2] = pk_bf16(v[4], v[5]); w[3] = pk_bf16(v[6], v[7]);
  }
  *(uint4*)(dst + (size_t)row * KAUG + c8) = make_uint4(w[0], w[1], w[2], w[3]);
}

// ---------------- pack A_aug for proj (inline softmax(rd)*plow/8) ----------------
__global__ __launch_bounds__(256) void cast_pack_proj(
    const float* __restrict__ xo, const float* __restrict__ rd,
    const float* __restrict__ plow, unsigned short* __restrict__ dst)
{
  int idx = blockIdx.x * 256 + threadIdx.x;
  int row = idx / 100, c8 = (idx % 100) * 8;
  unsigned int w[4];
  if (c8 < 768) {
    const float* s = xo + (size_t)row * 768 + c8;
    float4 a = *(const float4*)s;
    float4 b = *(const float4*)(s + 4);
    w[0] = pk_bf16(a.x, a.y); w[1] = pk_bf16(a.z, a.w);
    w[2] = pk_bf16(b.x, b.y); w[3] = pk_bf16(b.z, b.w);
  } else {
    float l0 = rd[row * 4 + 0], l1 = rd[row * 4 + 1], l2 = rd[row * 4 + 2], l3 = rd[row * 4 + 3];
    float m = fmaxf(fmaxf(l0, l1), fmaxf(l2, l3));
    float e0 = __expf(l0 - m), e1 = __expf(l1 - m), e2 = __expf(l2 - m), e3 = __expf(l3 - m);
    float inv = 0.125f / (e0 + e1 + e2 + e3);
    float rt[4] = { e0 * inv, e1 * inv, e2 * inv, e3 * inv };
    float v[8];
#pragma unroll
    for (int j = 0; j < 8; ++j) {
      int e = c8 - 768 + j;
      v[j] = (e < 32) ? rt[e >> 3] * plow[(size_t)row * 32 + e] : 0.f;
    }
    w[0] = pk_bf16(v[0], v[1]); w[1] = pk_bf16(v[2], v[3]);
    w[2] = pk_bf16(v[4], v[5]); w[3] = pk_bf16(v[6], v[7]);
  }
  *(uint4*)(dst + (size_t)row * KAUG + c8) = make_uint4(w[0], w[1], w[2], w[3]);
}

// ---------------- MFMA GEMM: C = A_aug @ W_aug^T + bias, K=800 ----------------
__global__ __launch_bounds__(256) void gemm_mfma(
    const unsigned short* __restrict__ A, const unsigned short* __restrict__ W,
    const float* __restrict__ bias, int mode, float* __restrict__ dst,
    unsigned short* __restrict__ qh, float* __restrict__ kmid,
    float* __restrict__ vb, unsigned short* __restrict__ kfh)
{
  const int t = threadIdx.x, w = t >> 6, l = t & 63;
  const int m = l & 15, quad = l >> 4;
  const int bm = blockIdx.y * 128 + (w >> 1) * 64;
  const int bn = blockIdx.x * 128 + (w & 1) * 64;
  f32x4 acc[4][4] = {};
  const unsigned short* Ab = A + (size_t)(bm + m) * KAUG;
  const unsigned short* Wb = W + (size_t)(bn + m) * KAUG;
  for (int kk = 0; kk < KAUG; kk += 32) {
    bf16x8 af[4], bf[4];
#pragma unroll
    for (int i = 0; i < 4; ++i) af[i] = *(const bf16x8*)(Ab + (size_t)i * 16 * KAUG + kk + quad * 8);
#pragma unroll
    for (int j = 0; j < 4; ++j) bf[j] = *(const bf16x8*)(Wb + (size_t)j * 16 * KAUG + kk + quad * 8);
#pragma unroll
    for (int i = 0; i < 4; ++i)
#pragma unroll
      for (int j = 0; j < 4; ++j)
        acc[i][j] = __builtin_amdgcn_mfma_f32_16x16x32_bf16(af[i], bf[j], acc[i][j], 0, 0, 0);
  }

  float bj[4];
#pragma unroll
  for (int j = 0; j < 4; ++j) bj[j] = bias[bn + j * 16 + m];

  if (mode == 2) {
#pragma unroll
    for (int i = 0; i < 4; ++i)
#pragma unroll
      for (int r = 0; r < 4; ++r) {
        int row = bm + i * 16 + quad * 4 + r;
#pragma unroll
        for (int j = 0; j < 4; ++j)
          dst[(size_t)row * 768 + bn + j * 16 + m] = acc[i][j][r] + bj[j];
      }
    return;
  }
  int g = (blockIdx.x * 128) / DIMc;           // uniform per block
#pragma unroll
  for (int j = 0; j < 4; ++j) {
    int col = bn + j * 16 + m;
    int jj = col - g * DIMc, hh = jj >> 6, d = jj & 63;
#pragma unroll
    for (int i = 0; i < 4; ++i)
#pragma unroll
      for (int r = 0; r < 4; ++r) {
        int row = bm + i * 16 + quad * 4 + r;
        int bb = row / NNtok, tt = row % NNtok;
        float v = acc[i][j][r] + bj[j];
        if (g == 0) {
          qh[((size_t)(bb * Hh + hh) * NNtok + tt) * Dd + d] = bf16_1(v * 0.125f);
        } else if (g == 1) {
          kfh[((size_t)(bb * Hh + hh) * 2560 + 1280 + tt) * Dd + d] = bf16_1(v);
          if (tt < 256) kmid[((size_t)(bb * Hh + hh) * 256 + tt) * Dd + d] = v;
        } else {
          vb[((size_t)(bb * Hh + hh) * NNtok + tt) * Dd + d] = v;
        }
      }
  }
}

// ---------------- radix helper: select bin from per-wave 256-bin hist ----------------
__device__ __forceinline__ void radix_sel(
    unsigned int* hist, int l, int& kk, int& ceq, unsigned int& bin)
{
  unsigned int h0 = hist[4 * l + 0], h1 = hist[4 * l + 1],
               h2 = hist[4 * l + 2], h3 = hist[4 * l + 3];
  unsigned int s3 = h3, s2 = h2 + s3, s1 = h1 + s2, s0 = h0 + s1;
  unsigned int tsum = s0;
#pragma unroll
  for (int off = 1; off < 64; off <<= 1) {
    unsigned int other = __shfl(tsum, l + off, 64);
    tsum += (l + off < 64) ? other : 0u;
  }
  unsigned int T = tsum - s0;   // suffix over lanes > l
  unsigned int Sv0 = T + s0, Sv1 = T + s1, Sv2 = T + s2, Sv3 = T + s3, Sv4 = T;
  int fb = -1, fkk = 0, fceq = 0;
  unsigned int ukk = (unsigned int)kk;
  if (Sv0 >= ukk && Sv1 < ukk) { fb = 4 * l + 0; fkk = (int)(ukk - Sv1); fceq = (int)(Sv0 - Sv1); }
  if (Sv1 >= ukk && Sv2 < ukk) { fb = 4 * l + 1; fkk = (int)(ukk - Sv2); fceq = (int)(Sv1 - Sv2); }
  if (Sv2 >= ukk && Sv3 < ukk) { fb = 4 * l + 2; fkk = (int)(ukk - Sv3); fceq = (int)(Sv2 - Sv3); }
  if (Sv3 >= ukk && Sv4 < ukk) { fb = 4 * l + 3; fkk = (int)(ukk - Sv4); fceq = (int)(Sv3 - Sv4); }
  unsigned long long mb = __ballot(fb >= 0);
  int src = __ffsll(mb) - 1;
  bin = (unsigned int)__shfl(fb, src, 64);
  kk  = __shfl(fkk, src, 64);
  ceq = __shfl(fceq, src, 64);
}

// ---------------- MFMA top-k attention v7: 8 rows/block, grouped prefetch,
//                  row-pair-interleaved stage-1 radix ----------------
template<int NK>
__global__ __launch_bounds__(256, 3) void attn_mfma7(
    const unsigned short* __restrict__ qh,   // (bh,1280,64) bf16
    const unsigned short* __restrict__ kf,   // (bh,NK,64)   bf16
    const unsigned short* __restrict__ vt,   // (bh,64,NK)   bf16 (V^T)
    int TK, int qrow0, float* __restrict__ xo, int nofs)
{
  constexpr int SCP = NK + 8;
  constexpr int W = NK / 128;          // score words per lane per row
  __shared__ alignas(16) unsigned short sc16[8][SCP];
  __shared__ unsigned int hist4[4][256];
  __shared__ float wavemax[4][8];
  __shared__ float rowinv[8];

  const int t = threadIdx.x, w = t >> 6, l = t & 63;
  const int bh = blockIdx.x % NBH;
  const int rb = blockIdx.x / NBH;
  const int b = bh / Hh, h = bh % Hh;
  const int qbase = qrow0 + rb * 8;
  const int m = l & 15, quad = l >> 4;

  // ---- Phase A: QK^T via MFMA (A rows 0-7 = q), 4-deep grouped prefetch ----
  bf16x8 aq0 = {0,0,0,0,0,0,0,0}, aq1 = {0,0,0,0,0,0,0,0};
  if (m < 8) {
    const unsigned short* qp = qh + ((size_t)bh * NNtok + qbase + m) * Dd + quad * 8;
    aq0 = *(const bf16x8*)qp;
    aq1 = *(const bf16x8*)(qp + 32);
  }
  float mx[4] = { -3.0e38f, -3.0e38f, -3.0e38f, -3.0e38f };  // rows quad*4+r
  constexpr int ITA = NK / 64;
  constexpr int GA = (ITA >= 4) ? 4 : ITA;
  const unsigned short* kpA = kf + (size_t)bh * NK * Dd + (size_t)(w * 16 + m) * Dd + quad * 8;
  bf16x8 kbuf[2][GA][2];
#pragma unroll
  for (int i = 0; i < GA; ++i) {
    kbuf[0][i][0] = *(const bf16x8*)(kpA + (size_t)i * 64 * Dd);
    kbuf[0][i][1] = *(const bf16x8*)(kpA + (size_t)i * 64 * Dd + 32);
  }
  int ab = 0;
  for (int g0 = 0; g0 < ITA; g0 += GA) {
    if (g0 + GA < ITA) {
#pragma unroll
      for (int i = 0; i < GA; ++i) {
        kbuf[1 - ab][i][0] = *(const bf16x8*)(kpA + (size_t)(g0 + GA + i) * 64 * Dd);
        kbuf[1 - ab][i][1] = *(const bf16x8*)(kpA + (size_t)(g0 + GA + i) * 64 * Dd + 32);
      }
    }
#pragma unroll
    for (int i = 0; i < GA; ++i) {
      int n0 = w * 16 + (g0 + i) * 64;
      f32x4 acc = {0.f, 0.f, 0.f, 0.f};
      acc = __builtin_amdgcn_mfma_f32_16x16x32_bf16(aq0, kbuf[ab][i][0], acc, 0, 0, 0);
      acc = __builtin_amdgcn_mfma_f32_16x16x32_bf16(aq1, kbuf[ab][i][1], acc, 0, 0, 0);
      if (quad < 2) {    // lanes 0-31 hold rows 0-7 (row = quad*4+reg), col = n0+m
#pragma unroll
        for (int r = 0; r < 4; ++r) {
          float v = acc[r];
          mx[r] = fmaxf(mx[r], v);
          sc16[quad * 4 + r][n0 + m] = bf16_1(v);
        }
      }
    }
    ab ^= 1;
  }
#pragma unroll
  for (int off = 1; off < 16; off <<= 1)
#pragma unroll
    for (int r = 0; r < 4; ++r) mx[r] = fmaxf(mx[r], __shfl_xor(mx[r], off, 64));
  if (l == 0) {
#pragma unroll
    for (int r = 0; r < 4; ++r) wavemax[w][r] = mx[r];
  }
  if (l == 16) {
#pragma unroll
    for (int r = 0; r < 4; ++r) wavemax[w][4 + r] = mx[r];
  }
  __syncthreads();

  // ---- Phase B: load both rows; stage-1 bit-plane INTERLEAVED (2 indep chains) ----
  const int r0i = w * 2, r1i = w * 2 + 1;
  unsigned int* sp0 = (unsigned int*)&sc16[r0i][0];
  unsigned int* sp1 = (unsigned int*)&sc16[r1i][0];
  unsigned int kw0[W], kw1[W];
#pragma unroll
  for (int j = 0; j < W; ++j) {
    unsigned int v0 = sp0[j * 64 + l];
    unsigned int v1 = sp1[j * 64 + l];
    kw0[j] = v0 ^ (((v0 >> 15) & 0x00010001u) * 0x7fffu + 0x80008000u);
    kw1[j] = v1 ^ (((v1 >> 15) & 0x00010001u) * 0x7fffu + 0x80008000u);
  }
  unsigned int pf0 = 0, pf1 = 0;
  int kk0 = TK, kk1 = TK;
#pragma unroll 1
  for (int bit = 15; bit >= 8; --bit) {
    unsigned int hm = (0xFFFFu << bit) & 0xFFFFu;
    unsigned int c0 = pf0 | (1u << bit), c1 = pf1 | (1u << bit);
    int cnt0 = 0, cnt1 = 0;
#pragma unroll
    for (int j = 0; j < W; ++j) {
      unsigned int a = kw0[j], bv = kw1[j];
      cnt0 += __popcll(__ballot((a & hm) == c0));
      cnt1 += __popcll(__ballot((bv & hm) == c1));
      cnt0 += __popcll(__ballot(((a >> 16) & hm) == c0));
      cnt1 += __popcll(__ballot(((bv >> 16) & hm) == c1));
    }
    if (cnt0 >= kk0) pf0 = c0; else kk0 -= cnt0;
    if (cnt1 >= kk1) pf1 = c1; else kk1 -= cnt1;
  }

  // ---- stage-2 + ties + exp per row (lambda inlines; kw stays in regs) ----
  auto finish = [&](unsigned int* kwp, unsigned int prefix, int kk, int row,
                    unsigned int* sp) {
    unsigned int* hist = hist4[w];
#pragma unroll
    for (int z = 0; z < 4; ++z) hist[l + z * 64] = 0u;
    const unsigned int pfx8 = prefix >> 8;
#pragma unroll
    for (int j = 0; j < W; ++j) {
      unsigned int k2 = kwp[j];
      unsigned int lo = k2 & 0xFFFFu, hi = k2 >> 16;
      if ((lo >> 8) == pfx8) atomicAdd(&hist[lo & 255u], 1u);
      if ((hi >> 8) == pfx8) atomicAdd(&hist[hi & 255u], 1u);
    }
    unsigned int b2;
    int ceq = 0;
    radix_sel(hist, l, kk, ceq, b2);
    const unsigned int Tkey = prefix | b2;
    const int need = kk;
    if (need < ceq) {   // ties at threshold: keep lowest indices (jax order)
      int seen = 0;
      unsigned long long below = (1ull << l) - 1ull;
#pragma unroll
      for (int j = 0; j < W; ++j) {
        unsigned int k2 = kwp[j];
        bool eq0 = ((k2 & 0xFFFFu) == Tkey);
        bool eq1 = ((k2 >> 16) == Tkey);
        unsigned long long m0 = __ballot(eq0), m1 = __ballot(eq1);
        int bfr = __popcll(m0 & below) + __popcll(m1 & below);
        if (eq0 && (seen + bfr) >= need) kwp[j] &= 0xFFFF0000u;
        if (eq1 && (seen + bfr + (eq0 ? 1 : 0)) >= need) kwp[j] &= 0x0000FFFFu;
        seen += __popcll(m0) + __popcll(m1);
      }
    }
    float rm = fmaxf(fmaxf(wavemax[0][row], wavemax[1][row]),
                     fmaxf(wavemax[2][row], wavemax[3][row]));
    float sum = 0.f;
#pragma unroll
    for (int j = 0; j < W; ++j) {
      unsigned int k2 = kwp[j];
      unsigned int lo = k2 & 0xFFFFu, hi = k2 >> 16;
      unsigned int mm = ((~k2 >> 15) & 0x00010001u) * 0x7fffu + 0x80008000u;
      unsigned int o2 = k2 ^ mm;   // back to bf16 bits
      float v0 = bf2f(o2 & 0xFFFFu);
      float v1 = bf2f(o2 >> 16);
      float w0 = (lo >= Tkey) ? __expf(v0 - rm) : 0.f;
      float w1 = (hi >= Tkey) ? __expf(v1 - rm) : 0.f;
      sp[j * 64 + l] = pk_bf16(w0, w1);
      sum += w0 + w1;
    }
#pragma unroll
    for (int off = 32; off; off >>= 1) sum += __shfl_xor(sum, off, 64);
    if (l == 0) rowinv[row] = 1.f / sum;
  };
  finish(kw0, pf0, kk0, r0i, sp0);
  finish(kw1, pf1, kk1, r1i, sp1);
  __syncthreads();

  // ---- Phase D: PV via MFMA (A rows 0-7 = weights), 4-deep grouped prefetch ----
  constexpr int ITD = NK / 32;
  constexpr int GD = (ITD >= 4) ? 4 : ITD;
  const unsigned short* vrow = vt + (size_t)bh * Dd * NK + (size_t)(w * 16 + m) * NK + quad * 8;
  f32x4 o = {0.f, 0.f, 0.f, 0.f};
  const bf16x8 zz = {0,0,0,0,0,0,0,0};
  bf16x8 vbuf[2][GD], wbuf[2][GD];
#pragma unroll
  for (int i = 0; i < GD; ++i) {
    vbuf[0][i] = *(const bf16x8*)(vrow + i * 32);
    wbuf[0][i] = (m < 8) ? *(const bf16x8*)&sc16[m][i * 32 + quad * 8] : zz;
  }
  int db = 0;
  for (int g0 = 0; g0 < ITD; g0 += GD) {
    if (g0 + GD < ITD) {
#pragma unroll
      for (int i = 0; i < GD; ++i) {
        vbuf[1 - db][i] = *(const bf16x8*)(vrow + (g0 + GD + i) * 32);
        wbuf[1 - db][i] = (m < 8) ? *(const bf16x8*)&sc16[m][(g0 + GD + i) * 32 + quad * 8] : zz;
      }
    }
#pragma unroll
    for (int i = 0; i < GD; ++i)
      o = __builtin_amdgcn_mfma_f32_16x16x32_bf16(wbuf[db][i], vbuf[db][i], o, 0, 0, 0);
    db ^= 1;
  }
  if (quad < 2) {
#pragma unroll
    for (int r = 0; r < 4; ++r) {
      int row = quad * 4 + r;
      int n = nofs + rb * 8 + row;
      xo[((size_t)b * NNtok + n) * DIMc + h * 64 + w * 16 + m] = o[r] * rowinv[row];
    }
  }
}

// ---------------- host ----------------
extern "C" void kernel_launch(void* const* d_in, const int* in_sizes, int n_in,
                              void* d_out, int out_size, void* d_ws, size_t ws_size,
                              hipStream_t stream)
{
  const float* x       = (const float*)d_in[0];
  const float* id_tot  = (const float*)d_in[1];
  const float* mem_k   = (const float*)d_in[2];
  const float* mem_v   = (const float*)d_in[3];
  const float* W_qkv   = (const float*)d_in[4];
  const float* b_qkv   = (const float*)d_in[5];
  const float* qkv_A   = (const float*)d_in[6];
  const float* qkv_B   = (const float*)d_in[7];
  const float* W_proj  = (const float*)d_in[8];
  const float* b_proj  = (const float*)d_in[9];
  const float* route_W = (const float*)d_in[10];
  const float* proj_A  = (const float*)d_in[11];
  const float* proj_B  = (const float*)d_in[12];
  const float* W_idk   = (const float*)d_in[13];
  const float* b_idk   = (const float*)d_in[14];
  const float* idk_A   = (const float*)d_in[15];
  const float* idk_B   = (const float*)d_in[16];
  const float* W_idv   = (const float*)d_in[17];
  const float* b_idv   = (const float*)d_in[18];
  const float* idv_A   = (const float*)d_in[19];
  const float* idv_B   = (const float*)d_in[20];

  float* ws   = (float*)d_ws;
  float* vb   = ws + OVb;
  float* xo   = ws + OXO;
  float* qlow = ws + OQL;
  float* IDK  = ws + OIDK;
  float* IDV  = ws + OIDV;
  float* lowk = ws + OLK;
  float* lowv = ws + OLV;
  float* rd   = ws + ORD;
  float* plow = ws + OPL;
  unsigned short* qh   = (unsigned short*)(ws + OQH);
  unsigned short* kfh  = (unsigned short*)(ws + OKFH);
  unsigned short* vth  = (unsigned short*)(ws + OVTH);
  unsigned short* kmh  = (unsigned short*)(ws + OKMH);
  unsigned short* vmth = (unsigned short*)(ws + OVMTH);
  unsigned short* Aa   = (unsigned short*)(ws + OAa);
  unsigned short* Wa   = (unsigned short*)(ws + OWa);
  unsigned short* Wa2  = (unsigned short*)(ws + OWa2);

  float* out  = (float*)d_out;
  float* kmid = out + KMID_OFF;
  float* vmid = out + VMID_OFF;

  // staging: mem_k cast, mem_v transpose, both W_aug builds — one launch
  prep<<<7680, 256, 0, stream>>>(mem_k, mem_v, W_qkv, qkv_B, W_proj, proj_B,
                                 kfh, vth, Wa, Wa2);

  // LoRA downs
  dot_small<<<1280, 256, 0, stream>>>(x, qkv_A, qlow, 24);
  dot_id<<<256, 256, 0, stream>>>(id_tot, idk_A, idv_A, lowk, lowv);

  // QKV via MFMA with augmented K (fused LoRA)
  cast_pack<<<2000, 256, 0, stream>>>(x, qlow, Aa, 24);
  gemm_mfma<<<dim3(18, 40), 256, 0, stream>>>(Aa, Wa, b_qkv, 0, nullptr,
                                              qh, kmid, vb, kfh);
  // ID_V (fp32 GEMM) + ID_K (1+tanh) — one launch
  idv_idk<<<448, 256, 0, stream>>>(id_tot, W_idv, b_idv, lowv, idv_B, IDV,
                                   W_idk, b_idk, lowk, idk_B, IDK);
  // outputs k_m_id / v_m_id; vb rows 0-255 updated in place
  fixup_kernel<<<3072, 256, 0, stream>>>(vb, IDK, IDV, kmid, vmid, kmh);

  // V^T bf16 staging (post-fixup)
  transpose_post<<<1152, 256, 0, stream>>>(vb, vth, vmth);

  // attention: 8 rows/block (XCD-swizzled: blockIdx = rb*48 + bh)
  attn_mfma7<256><<<1536, 256, 0, stream>>>(qh, kmh, vmth, 128, 0, xo, 0);
  attn_mfma7<2560><<<6144, 256, 0, stream>>>(qh, kfh, vth, 640, 256, xo, 256);

  // routed output projection
  dot_rp<<<1280, 256, 0, stream>>>(xo, route_W, proj_A, rd, plow);
  cast_pack_proj<<<2000, 256, 0, stream>>>(xo, rd, plow, Aa);
  gemm_mfma<<<dim3(6, 40), 256, 0, stream>>>(Aa, Wa2, b_proj, 2, out,
                                             nullptr, nullptr, nullptr, nullptr);
}